// Round 9
// baseline (295.055 us; speedup 1.0000x reference)
//
#include <hip/hip_runtime.h>
#include <hip/hip_bf16.h>

#define NN 10000
#define NE 160000
#define NET 170000   // edges + self loops
#define CAPE 250048  // padded CSR capacity (mult of 8; NET + 7*NN < CAPE)
#define IN_DIM 512
#define D1 1024      // HEADS*HID
#define HEADS 4
#define HID 256
#define OUT_DIM 512
#define NEG_SLOPE 0.2f

typedef __attribute__((ext_vector_type(8))) short bf16x8;
typedef __attribute__((ext_vector_type(4))) float f32x4;

__device__ inline float b2f(unsigned short b) {
    union { unsigned u; float f; } x; x.u = ((unsigned)b) << 16; return x.f;
}
__device__ inline unsigned short f2b(float f) {
    union { float f; unsigned u; } x; x.f = f;
    unsigned u = x.u;
    unsigned r = u + 0x7FFFu + ((u >> 16) & 1u);
    return (unsigned short)(r >> 16);
}
__device__ inline float lrelu(float v) { return v > 0.f ? v : NEG_SLOPE * v; }

// ---- init: zero counts/cursor + padded csr; block 0 detects edge dtype
__global__ void init_kernel(const int* ei32, int* flag, int* counts, int* cursor,
                            int* csr_src) {
    int i = blockIdx.x * blockDim.x + threadIdx.x;
    if (i < NN) { counts[i] = 0; cursor[i] = 0; }
    for (int k = i; k < CAPE; k += 40 * 256) csr_src[k] = 0;
    if (blockIdx.x == 0) {
        __shared__ int nz;
        if (threadIdx.x == 0) nz = 0;
        __syncthreads();
        int acc = 0;
        for (int k = threadIdx.x; k < 500; k += 256) acc |= ei32[2 * k + 1];
        if (acc) atomicOr(&nz, 1);
        __syncthreads();
        if (threadIdx.x == 0) flag[0] = (nz == 0) ? 1 : 0;
    }
}

__device__ inline void load_edge(const void* ei, int f64, int e, int& s, int& d) {
    if (f64) {
        const long long* p = (const long long*)ei;
        s = (int)p[e]; d = (int)p[NE + e];
    } else {
        const int* p = (const int*)ei;
        s = p[e]; d = p[NE + e];
    }
}

__global__ void count_kernel(const void* ei, const int* flag, int* counts) {
    int e = blockIdx.x * blockDim.x + threadIdx.x;
    if (e >= NET) return;
    int s, d;
    if (e < NE) load_edge(ei, *flag, e, s, d);
    else d = e - NE;
    atomicAdd(&counts[d], 1);
}

// ---- scan over PADDED counts (round up to 8 -> 32B-aligned segments)
__global__ __launch_bounds__(256) void scan_kernel(const int* counts, int* indptr) {
    __shared__ int part[256];
    int t = threadIdx.x;
    int base = t * 40;
    int local[40];
    int sum = 0;
#pragma unroll
    for (int k = 0; k < 40; k++) {
        int i = base + k;
        int c = (i < NN) ? ((counts[i] + 7) & ~7) : 0;
        local[k] = sum;
        sum += c;
    }
    part[t] = sum;
    __syncthreads();
    for (int off = 1; off < 256; off <<= 1) {
        int v = (t >= off) ? part[t - off] : 0;
        __syncthreads();
        part[t] += v;
        __syncthreads();
    }
    int excl = part[t] - sum;
#pragma unroll
    for (int k = 0; k < 40; k++) {
        int i = base + k;
        if (i < NN) indptr[i] = excl + local[k];
    }
    if (t == 255) indptr[NN] = part[255];
}

__global__ void fill_kernel(const void* ei, const int* flag, const int* indptr,
                            int* cursor, int* csr_src) {
    int e = blockIdx.x * blockDim.x + threadIdx.x;
    if (e >= NET) return;
    int s, d;
    if (e < NE) load_edge(ei, *flag, e, s, d);
    else { s = e - NE; d = s; }
    int pos = indptr[d] + atomicAdd(&cursor[d], 1);
    csr_src[pos] = s;
}

// ---- prep: fused x->bf16 convert + 3 weight transposes (sectioned 1D grid)
__device__ void tpose_tile(const float* __restrict__ in, unsigned short* __restrict__ out,
                           int R, int C, int bx, int by) {
    __shared__ float tile[32][33];
    int tx = threadIdx.x & 31, ty = threadIdx.x >> 5;
    int c = bx * 32 + tx;
#pragma unroll
    for (int r0 = 0; r0 < 32; r0 += 8) {
        int r = by * 32 + ty + r0;
        tile[ty + r0][tx] = in[(size_t)r * C + c];
    }
    __syncthreads();
    int oc = by * 32 + tx;
#pragma unroll
    for (int r0 = 0; r0 < 32; r0 += 8) {
        int orow = bx * 32 + ty + r0;
        out[(size_t)orow * R + oc] = f2b(tile[tx][ty + r0]);
    }
}

#define CVT_NB 5000   // NN*IN_DIM/4/256
#define TP1_NB 512    // (D1/32)*(IN_DIM/32)
#define TP2_NB 1024   // (D1/32)*(D1/32)
#define TP3_NB 512    // (OUT_DIM/32)*(D1/32)
__global__ __launch_bounds__(256) void prep_kernel(
    const float* __restrict__ x, unsigned short* __restrict__ xb,
    const float* __restrict__ W1, unsigned short* __restrict__ W1t,
    const float* __restrict__ W2, unsigned short* __restrict__ W2t,
    const float* __restrict__ fcW, unsigned short* __restrict__ fcWt) {
    int b = blockIdx.x;
    if (b < CVT_NB) {
        int i = b * 256 + threadIdx.x;
        float4 v = reinterpret_cast<const float4*>(x)[i];
        ushort4 o;
        o.x = f2b(v.x); o.y = f2b(v.y); o.z = f2b(v.z); o.w = f2b(v.w);
        reinterpret_cast<ushort4*>(xb)[i] = o;
        return;
    }
    b -= CVT_NB;
    if (b < TP1_NB) { tpose_tile(W1, W1t, IN_DIM, D1, b & 31, b >> 5); return; }
    b -= TP1_NB;
    if (b < TP2_NB) { tpose_tile(W2, W2t, D1, D1, b & 31, b >> 5); return; }
    b -= TP2_NB;
    tpose_tile(fcW, fcWt, D1, OUT_DIM, b & 15, b >> 4);
}

// ---- C[M][N] = A[M][K](bf16) @ B[N][K](bf16)^T
// 128x128 tile, BK=64, 4 waves (2x2 of 64x64), global_load_lds width 16,
// XOR-swizzled LDS, bijective XCD-aware block swizzle.
#define BM 128
#define BN 128
#define BK 64
__global__ __launch_bounds__(256) void gemm128(
    const unsigned short* __restrict__ A, const unsigned short* __restrict__ B,
    const float* __restrict__ bias, float* __restrict__ Cf, unsigned short* __restrict__ Cb,
    int M, int N, int K, int NB) {
    __shared__ __align__(16) unsigned short As[BM * BK];  // 16 KB
    __shared__ __align__(16) unsigned short Bs[BN * BK];  // 16 KB
    int t = threadIdx.x;
    int nwg = gridDim.x;
    int q = nwg >> 3, r = nwg & 7;
    int xcd = blockIdx.x & 7, jj = blockIdx.x >> 3;
    int wg = (xcd < r ? xcd * (q + 1) : r * (q + 1) + (xcd - r) * q) + jj;
    int row0 = (wg / NB) * BM, col0 = (wg % NB) * BN;

    int w = t >> 6, l = t & 63;
    int wr = w >> 1, wc = w & 1;
    f32x4 acc[4][4] = {};

    int srow = w * 8 + (l >> 3);                 // row within 32-row issue chunk
    int scs = (((l & 7) ^ (l >> 3)) * 8);        // source col in shorts (inverse swizzle)
    const unsigned short* ap0 = A + (size_t)min(row0 +  0 + srow, M - 1) * K + scs;
    const unsigned short* ap1 = A + (size_t)min(row0 + 32 + srow, M - 1) * K + scs;
    const unsigned short* ap2 = A + (size_t)min(row0 + 64 + srow, M - 1) * K + scs;
    const unsigned short* ap3 = A + (size_t)min(row0 + 96 + srow, M - 1) * K + scs;
    const unsigned short* bp0 = B + (size_t)(col0 +  0 + srow) * K + scs;
    const unsigned short* bp1 = B + (size_t)(col0 + 32 + srow) * K + scs;
    const unsigned short* bp2 = B + (size_t)(col0 + 64 + srow) * K + scs;
    const unsigned short* bp3 = B + (size_t)(col0 + 96 + srow) * K + scs;
    unsigned short* asd0 = As + 0 * 2048 + w * 512;
    unsigned short* asd1 = As + 1 * 2048 + w * 512;
    unsigned short* asd2 = As + 2 * 2048 + w * 512;
    unsigned short* asd3 = As + 3 * 2048 + w * 512;
    unsigned short* bsd0 = Bs + 0 * 2048 + w * 512;
    unsigned short* bsd1 = Bs + 1 * 2048 + w * 512;
    unsigned short* bsd2 = Bs + 2 * 2048 + w * 512;
    unsigned short* bsd3 = Bs + 3 * 2048 + w * 512;

    int rr = l & 15;
    int rb = (rr & 7) << 4;
    int kb0 = (l >> 4) << 4;
    const char* Ab = (const char*)As;
    const char* Bb = (const char*)Bs;

#define GLD(src, dst) __builtin_amdgcn_global_load_lds( \
        (const __attribute__((address_space(1))) void*)(src), \
        (__attribute__((address_space(3))) void*)(dst), 16, 0, 0)

    for (int k0 = 0; k0 < K; k0 += BK) {
        GLD(ap0, asd0); GLD(ap1, asd1); GLD(ap2, asd2); GLD(ap3, asd3);
        GLD(bp0, bsd0); GLD(bp1, bsd1); GLD(bp2, bsd2); GLD(bp3, bsd3);
        ap0 += BK; ap1 += BK; ap2 += BK; ap3 += BK;
        bp0 += BK; bp1 += BK; bp2 += BK; bp3 += BK;
        __syncthreads();

#pragma unroll
        for (int ks = 0; ks < 2; ks++) {
            int kb = ((ks << 6) | kb0) ^ rb;
            bf16x8 af[4], bfv[4];
#pragma unroll
            for (int mi = 0; mi < 4; mi++)
                af[mi] = *reinterpret_cast<const bf16x8*>(
                    Ab + (wr * 64 + mi * 16 + rr) * 128 + kb);
#pragma unroll
            for (int ni = 0; ni < 4; ni++)
                bfv[ni] = *reinterpret_cast<const bf16x8*>(
                    Bb + (wc * 64 + ni * 16 + rr) * 128 + kb);
#pragma unroll
            for (int mi = 0; mi < 4; mi++)
#pragma unroll
                for (int ni = 0; ni < 4; ni++)
                    acc[mi][ni] = __builtin_amdgcn_mfma_f32_16x16x32_bf16(
                        af[mi], bfv[ni], acc[mi][ni], 0, 0, 0);
        }
        __syncthreads();
    }
#undef GLD

    int c_l = l & 15, r_h = (l >> 4) * 4;
#pragma unroll
    for (int mi = 0; mi < 4; mi++)
#pragma unroll
        for (int ni = 0; ni < 4; ni++) {
            int gc = col0 + wc * 64 + ni * 16 + c_l;
#pragma unroll
            for (int j = 0; j < 4; j++) {
                int gr = row0 + wr * 64 + mi * 16 + r_h + j;
                if (gr < M) {
                    float v = acc[mi][ni][j];
                    if (bias) v += bias[gc];
                    if (Cf) Cf[(size_t)gr * N + gc] = v;
                    if (Cb) Cb[(size_t)gr * N + gc] = f2b(v);
                }
            }
        }
}

// ---- a_src/a_dst dots: wave-per-node. Lane l: head l>>4, 16 channels.
__global__ __launch_bounds__(256) void att_kernel(const unsigned short* __restrict__ hb,
                                                  const float* __restrict__ att_s,
                                                  const float* __restrict__ att_d,
                                                  float* __restrict__ aS, float* __restrict__ aD) {
    int node = blockIdx.x * 4 + (threadIdx.x >> 6);
    int l = threadIdx.x & 63;
    int head = l >> 4, qq = l & 15;
    const unsigned short* hrow = hb + (size_t)node * D1 + head * HID + qq * 16;
    bf16x8 h0 = *reinterpret_cast<const bf16x8*>(hrow);
    bf16x8 h1 = *reinterpret_cast<const bf16x8*>(hrow + 8);
    const float* asp = att_s + head * HID + qq * 16;
    const float* adp = att_d + head * HID + qq * 16;
    float ps = 0.f, pd = 0.f;
#pragma unroll
    for (int c = 0; c < 8; c++) {
        float hv = b2f((unsigned short)h0[c]);
        float hw = b2f((unsigned short)h1[c]);
        ps += hv * asp[c] + hw * asp[8 + c];
        pd += hv * adp[c] + hw * adp[8 + c];
    }
#pragma unroll
    for (int off = 1; off <= 8; off <<= 1) {
        ps += __shfl_xor(ps, off);
        pd += __shfl_xor(pd, off);
    }
    if (qq == 0) {
        aS[node * HEADS + head] = ps;
        aD[node * HEADS + head] = pd;
    }
}

// ---- alpha precompute over PADDED segments: e per (edge, head) head-major,
// zeros for pad slots; einv[node][h] = 1/sum(e).
__global__ __launch_bounds__(256) void alpha_kernel(
    const float* __restrict__ aS, const float* __restrict__ aD,
    const int* __restrict__ indptr, const int* __restrict__ counts,
    const int* __restrict__ csr_src,
    float* __restrict__ alpha, float* __restrict__ einv) {
    int node = blockIdx.x * 4 + (threadIdx.x >> 6);
    int l = threadIdx.x & 63;
    int beg = indptr[node];
    int pdeg = indptr[node + 1] - beg;
    int rdeg = counts[node];
    float4 ad = *reinterpret_cast<const float4*>(aD + node * HEADS);
    float s0 = 0.f, s1 = 0.f, s2 = 0.f, s3 = 0.f;
    for (int j = l; j < pdeg; j += 64) {
        int s = csr_src[beg + j];
        float4 a = *reinterpret_cast<const float4*>(aS + s * HEADS);
        bool real = j < rdeg;
        float e0 = real ? __expf(lrelu(a.x + ad.x)) : 0.f;
        float e1 = real ? __expf(lrelu(a.y + ad.y)) : 0.f;
        float e2 = real ? __expf(lrelu(a.z + ad.z)) : 0.f;
        float e3 = real ? __expf(lrelu(a.w + ad.w)) : 0.f;
        alpha[0 * CAPE + beg + j] = e0;
        alpha[1 * CAPE + beg + j] = e1;
        alpha[2 * CAPE + beg + j] = e2;
        alpha[3 * CAPE + beg + j] = e3;
        s0 += e0; s1 += e1; s2 += e2; s3 += e3;
    }
#pragma unroll
    for (int off = 32; off; off >>= 1) {
        s0 += __shfl_xor(s0, off);
        s1 += __shfl_xor(s1, off);
        s2 += __shfl_xor(s2, off);
        s3 += __shfl_xor(s3, off);
    }
    if (l == 0) {
        float4 iv;
        iv.x = 1.f / (s0 + 1e-16f);
        iv.y = 1.f / (s1 + 1e-16f);
        iv.z = 1.f / (s2 + 1e-16f);
        iv.w = 1.f / (s3 + 1e-16f);
        *reinterpret_cast<float4*>(einv + node * HEADS) = iv;
    }
}

// ---- aggregation: column-sliced, packed. Lane l = (quarter q=l>>4, chan c=l&15).
// Each gather instr fetches 4 edges x 128 cols (16B/lane). cs/alpha via
// broadcast int4/float4 (padded, 32B-aligned segments -> no tails, no clamps).
// Per 8 edges: 6 VMEM instrs (was 24). Cross-quarter combine: shfl 16,32.
__global__ __launch_bounds__(256) void agg_kernel(const unsigned short* __restrict__ hb,
                                                  const float* __restrict__ alpha,
                                                  const float* __restrict__ einv,
                                                  const int* __restrict__ indptr,
                                                  const int* __restrict__ csr_src,
                                                  const float* __restrict__ bias,
                                                  unsigned short* __restrict__ outb) {
    int slice = blockIdx.x & 7;
    int node = (blockIdx.x >> 3) * 4 + (threadIdx.x >> 6);
    int l = threadIdx.x & 63;
    int q = l >> 4;          // edge sub-group
    int c = l & 15;          // channel group (8 shorts)
    int head = slice >> 1;
    int cbase = slice * 128 + c * 8;
    int beg = indptr[node];
    int pdeg = indptr[node + 1] - beg;
    const int* cs = csr_src + beg;
    const float* ap = alpha + head * CAPE + beg;
    const unsigned short* hp = hb + cbase;
    float a0 = 0.f, a1 = 0.f, a2 = 0.f, a3 = 0.f;
    float a4 = 0.f, a5 = 0.f, a6 = 0.f, a7 = 0.f;
    for (int j = 0; j < pdeg; j += 8) {
        int4 sA = *reinterpret_cast<const int4*>(cs + j);
        int4 sB = *reinterpret_cast<const int4*>(cs + j + 4);
        float4 wA = *reinterpret_cast<const float4*>(ap + j);
        float4 wB = *reinterpret_cast<const float4*>(ap + j + 4);
        int sa = (q & 2) ? ((q & 1) ? sA.w : sA.z) : ((q & 1) ? sA.y : sA.x);
        int sb = (q & 2) ? ((q & 1) ? sB.w : sB.z) : ((q & 1) ? sB.y : sB.x);
        float wa = (q & 2) ? ((q & 1) ? wA.w : wA.z) : ((q & 1) ? wA.y : wA.x);
        float wb = (q & 2) ? ((q & 1) ? wB.w : wB.z) : ((q & 1) ? wB.y : wB.x);
        bf16x8 va = *reinterpret_cast<const bf16x8*>(hp + (size_t)sa * D1);
        bf16x8 vb = *reinterpret_cast<const bf16x8*>(hp + (size_t)sb * D1);
        a0 += wa * b2f((unsigned short)va[0]) + wb * b2f((unsigned short)vb[0]);
        a1 += wa * b2f((unsigned short)va[1]) + wb * b2f((unsigned short)vb[1]);
        a2 += wa * b2f((unsigned short)va[2]) + wb * b2f((unsigned short)vb[2]);
        a3 += wa * b2f((unsigned short)va[3]) + wb * b2f((unsigned short)vb[3]);
        a4 += wa * b2f((unsigned short)va[4]) + wb * b2f((unsigned short)vb[4]);
        a5 += wa * b2f((unsigned short)va[5]) + wb * b2f((unsigned short)vb[5]);
        a6 += wa * b2f((unsigned short)va[6]) + wb * b2f((unsigned short)vb[6]);
        a7 += wa * b2f((unsigned short)va[7]) + wb * b2f((unsigned short)vb[7]);
    }
#pragma unroll
    for (int off = 16; off <= 32; off <<= 1) {
        a0 += __shfl_xor(a0, off); a1 += __shfl_xor(a1, off);
        a2 += __shfl_xor(a2, off); a3 += __shfl_xor(a3, off);
        a4 += __shfl_xor(a4, off); a5 += __shfl_xor(a5, off);
        a6 += __shfl_xor(a6, off); a7 += __shfl_xor(a7, off);
    }
    if (q == 0) {
        float inv = einv[node * HEADS + head];
        float4 b0 = *reinterpret_cast<const float4*>(bias + cbase);
        float4 b1 = *reinterpret_cast<const float4*>(bias + cbase + 4);
        bf16x8 o;
        o[0] = (short)f2b(fmaxf(a0 * inv + b0.x, 0.f));
        o[1] = (short)f2b(fmaxf(a1 * inv + b0.y, 0.f));
        o[2] = (short)f2b(fmaxf(a2 * inv + b0.z, 0.f));
        o[3] = (short)f2b(fmaxf(a3 * inv + b0.w, 0.f));
        o[4] = (short)f2b(fmaxf(a4 * inv + b1.x, 0.f));
        o[5] = (short)f2b(fmaxf(a5 * inv + b1.y, 0.f));
        o[6] = (short)f2b(fmaxf(a6 * inv + b1.z, 0.f));
        o[7] = (short)f2b(fmaxf(a7 * inv + b1.w, 0.f));
        *reinterpret_cast<bf16x8*>(outb + (size_t)node * D1 + cbase) = o;
    }
}

extern "C" void kernel_launch(void* const* d_in, const int* in_sizes, int n_in,
                              void* d_out, int out_size, void* d_ws, size_t ws_size,
                              hipStream_t stream) {
    const float* x   = (const float*)d_in[0];
    const void*  ei  = d_in[1];
    const float* W1  = (const float*)d_in[2];
    const float* as1 = (const float*)d_in[3];
    const float* ad1 = (const float*)d_in[4];
    const float* b1  = (const float*)d_in[5];
    const float* W2  = (const float*)d_in[6];
    const float* as2 = (const float*)d_in[7];
    const float* ad2 = (const float*)d_in[8];
    const float* b2  = (const float*)d_in[9];
    const float* fcW = (const float*)d_in[10];
    const float* fcb = (const float*)d_in[11];
    float* out = (float*)d_out;

    char* ws = (char*)d_ws;
    size_t o = 0;
    auto carve = [&](size_t bytes) -> char* {
        char* p = ws + o;
        o = (o + bytes + 255) & ~(size_t)255;
        return p;
    };
    unsigned short* xb   = (unsigned short*)carve((size_t)NN * IN_DIM * 2);
    unsigned short* hb   = (unsigned short*)carve((size_t)NN * D1 * 2);
    unsigned short* x2b  = (unsigned short*)carve((size_t)NN * D1 * 2);
    unsigned short* W1t  = (unsigned short*)carve((size_t)D1 * IN_DIM * 2);
    unsigned short* W2t  = (unsigned short*)carve((size_t)D1 * D1 * 2);
    unsigned short* fcWt = (unsigned short*)carve((size_t)OUT_DIM * D1 * 2);
    float* aS    = (float*)carve((size_t)NN * HEADS * 4);
    float* aD    = (float*)carve((size_t)NN * HEADS * 4);
    float* alpha = (float*)carve((size_t)CAPE * HEADS * 4);
    float* einv  = (float*)carve((size_t)NN * HEADS * 4);
    int* counts = (int*)carve((size_t)NN * 4);
    int* cursor = (int*)carve((size_t)NN * 4);
    int* indptr = (int*)carve((size_t)(NN + 1) * 4);
    int* csr_src= (int*)carve((size_t)CAPE * 4);
    int* flag   = (int*)carve(4);
    (void)ws_size; (void)in_sizes; (void)n_in; (void)out_size;

    // CSR build (padded segments, dtype-agnostic edge loads)
    init_kernel<<<(NN + 255) / 256, 256, 0, stream>>>((const int*)ei, flag, counts, cursor, csr_src);
    count_kernel<<<(NET + 255) / 256, 256, 0, stream>>>(ei, flag, counts);
    scan_kernel<<<1, 256, 0, stream>>>(counts, indptr);
    fill_kernel<<<(NET + 255) / 256, 256, 0, stream>>>(ei, flag, indptr, cursor, csr_src);

    // fused conversions (cvt + 3 transposes)
    prep_kernel<<<CVT_NB + TP1_NB + TP2_NB + TP3_NB, 256, 0, stream>>>(
        x, xb, W1, W1t, W2, W2t, fcW, fcWt);

    const int MB = (NN + BM - 1) / BM;  // 79
    // layer 1
    gemm128<<<MB * (D1 / BN), 256, 0, stream>>>(xb, W1t, nullptr, nullptr, hb,
                                                NN, D1, IN_DIM, D1 / BN);
    att_kernel<<<NN / 4, 256, 0, stream>>>(hb, as1, ad1, aS, aD);
    alpha_kernel<<<NN / 4, 256, 0, stream>>>(aS, aD, indptr, counts, csr_src, alpha, einv);
    agg_kernel<<<(NN / 4) * 8, 256, 0, stream>>>(hb, alpha, einv, indptr, csr_src, b1, x2b);
    // layer 2
    gemm128<<<MB * (D1 / BN), 256, 0, stream>>>(x2b, W2t, nullptr, nullptr, hb,
                                                NN, D1, D1, D1 / BN);
    att_kernel<<<NN / 4, 256, 0, stream>>>(hb, as2, ad2, aS, aD);
    alpha_kernel<<<NN / 4, 256, 0, stream>>>(aS, aD, indptr, counts, csr_src, alpha, einv);
    agg_kernel<<<(NN / 4) * 8, 256, 0, stream>>>(hb, alpha, einv, indptr, csr_src, b2, x2b);
    // final fc (bias, f32 out)
    gemm128<<<MB * (OUT_DIM / BN), 256, 0, stream>>>(x2b, fcWt, fcb, out, nullptr,
                                                     NN, OUT_DIM, D1, OUT_DIM / BN);
}

// Round 10
// 240.928 us; speedup vs baseline: 1.2247x; 1.2247x over previous
//
#include <hip/hip_runtime.h>
#include <hip/hip_bf16.h>

#define NN 10000
#define NE 160000
#define NET 170000   // edges + self loops
#define IN_DIM 512
#define D1 1024      // HEADS*HID
#define HEADS 4
#define HID 256
#define OUT_DIM 512
#define NEG_SLOPE 0.2f

typedef __attribute__((ext_vector_type(8))) short bf16x8;
typedef __attribute__((ext_vector_type(4))) float f32x4;

__device__ inline float b2f(unsigned short b) {
    union { unsigned u; float f; } x; x.u = ((unsigned)b) << 16; return x.f;
}
__device__ inline unsigned short f2b(float f) {
    union { float f; unsigned u; } x; x.f = f;
    unsigned u = x.u;
    unsigned r = u + 0x7FFFu + ((u >> 16) & 1u);
    return (unsigned short)(r >> 16);
}
__device__ inline float lrelu(float v) { return v > 0.f ? v : NEG_SLOPE * v; }

// ---- init: zero counts/cursor; block 0 detects edge_index dtype
__global__ void init_kernel(const int* ei32, int* flag, int* counts, int* cursor) {
    int i = blockIdx.x * blockDim.x + threadIdx.x;
    if (i < NN) { counts[i] = 0; cursor[i] = 0; }
    if (blockIdx.x == 0) {
        __shared__ int nz;
        if (threadIdx.x == 0) nz = 0;
        __syncthreads();
        int acc = 0;
        for (int k = threadIdx.x; k < 500; k += 256) acc |= ei32[2 * k + 1];
        if (acc) atomicOr(&nz, 1);
        __syncthreads();
        if (threadIdx.x == 0) flag[0] = (nz == 0) ? 1 : 0;
    }
}

__device__ inline void load_edge(const void* ei, int f64, int e, int& s, int& d) {
    if (f64) {
        const long long* p = (const long long*)ei;
        s = (int)p[e]; d = (int)p[NE + e];
    } else {
        const int* p = (const int*)ei;
        s = p[e]; d = p[NE + e];
    }
}

__global__ void count_kernel(const void* ei, const int* flag, int* counts) {
    int e = blockIdx.x * blockDim.x + threadIdx.x;
    if (e >= NET) return;
    int s, d;
    if (e < NE) load_edge(ei, *flag, e, s, d);
    else d = e - NE;
    atomicAdd(&counts[d], 1);
}

__global__ __launch_bounds__(256) void scan_kernel(const int* counts, int* indptr) {
    __shared__ int part[256];
    int t = threadIdx.x;
    int base = t * 40;
    int local[40];
    int sum = 0;
#pragma unroll
    for (int k = 0; k < 40; k++) {
        int i = base + k;
        int c = (i < NN) ? counts[i] : 0;
        local[k] = sum;
        sum += c;
    }
    part[t] = sum;
    __syncthreads();
    for (int off = 1; off < 256; off <<= 1) {
        int v = (t >= off) ? part[t - off] : 0;
        __syncthreads();
        part[t] += v;
        __syncthreads();
    }
    int excl = part[t] - sum;
#pragma unroll
    for (int k = 0; k < 40; k++) {
        int i = base + k;
        if (i < NN) indptr[i] = excl + local[k];
    }
    if (t == 255) indptr[NN] = part[255];
}

__global__ void fill_kernel(const void* ei, const int* flag, const int* indptr,
                            int* cursor, int* csr_src) {
    int e = blockIdx.x * blockDim.x + threadIdx.x;
    if (e >= NET) return;
    int s, d;
    if (e < NE) load_edge(ei, *flag, e, s, d);
    else { s = e - NE; d = s; }
    int pos = indptr[d] + atomicAdd(&cursor[d], 1);
    csr_src[pos] = s;
}

// ---- prep: fused x->bf16 convert + 3 weight transposes (sectioned 1D grid)
__device__ void tpose_tile(const float* __restrict__ in, unsigned short* __restrict__ out,
                           int R, int C, int bx, int by) {
    __shared__ float tile[32][33];
    int tx = threadIdx.x & 31, ty = threadIdx.x >> 5;
    int c = bx * 32 + tx;
#pragma unroll
    for (int r0 = 0; r0 < 32; r0 += 8) {
        int r = by * 32 + ty + r0;
        tile[ty + r0][tx] = in[(size_t)r * C + c];
    }
    __syncthreads();
    int oc = by * 32 + tx;
#pragma unroll
    for (int r0 = 0; r0 < 32; r0 += 8) {
        int orow = bx * 32 + ty + r0;
        out[(size_t)orow * R + oc] = f2b(tile[tx][ty + r0]);
    }
}

#define CVT_NB 5000   // NN*IN_DIM/4/256
#define TP1_NB 512    // (D1/32)*(IN_DIM/32)
#define TP2_NB 1024   // (D1/32)*(D1/32)
#define TP3_NB 512    // (OUT_DIM/32)*(D1/32)
__global__ __launch_bounds__(256) void prep_kernel(
    const float* __restrict__ x, unsigned short* __restrict__ xb,
    const float* __restrict__ W1, unsigned short* __restrict__ W1t,
    const float* __restrict__ W2, unsigned short* __restrict__ W2t,
    const float* __restrict__ fcW, unsigned short* __restrict__ fcWt) {
    int b = blockIdx.x;
    if (b < CVT_NB) {
        int i = b * 256 + threadIdx.x;
        float4 v = reinterpret_cast<const float4*>(x)[i];
        ushort4 o;
        o.x = f2b(v.x); o.y = f2b(v.y); o.z = f2b(v.z); o.w = f2b(v.w);
        reinterpret_cast<ushort4*>(xb)[i] = o;
        return;
    }
    b -= CVT_NB;
    if (b < TP1_NB) { tpose_tile(W1, W1t, IN_DIM, D1, b & 31, b >> 5); return; }
    b -= TP1_NB;
    if (b < TP2_NB) { tpose_tile(W2, W2t, D1, D1, b & 31, b >> 5); return; }
    b -= TP2_NB;
    tpose_tile(fcW, fcWt, D1, OUT_DIM, b & 15, b >> 4);
}

// ---- C[M][N] = A[M][K](bf16) @ B[N][K](bf16)^T ; templated tile TBMxTBN,
// BK=64, 4 waves (2x2), global_load_lds width 16, XOR-swizzled LDS,
// bijective XCD-aware block swizzle. Smaller BN -> more blocks/CU so
// barrier drains overlap across co-resident blocks.
template<int TBM, int TBN>
__global__ __launch_bounds__(256) void gemmT(
    const unsigned short* __restrict__ A, const unsigned short* __restrict__ B,
    const float* __restrict__ bias, float* __restrict__ Cf, unsigned short* __restrict__ Cb,
    int M, int N, int K, int NB) {
    constexpr int FM = TBM / 32;    // fragments per wave (M)
    constexpr int FN = TBN / 32;    // fragments per wave (N)
    constexpr int AISS = TBM / 32;  // 32-row staging issues for A
    constexpr int BISS = TBN / 32;
    __shared__ __align__(16) unsigned short As[TBM * 64];
    __shared__ __align__(16) unsigned short Bs[TBN * 64];
    int t = threadIdx.x;
    int nwg = gridDim.x;
    int q = nwg >> 3, r = nwg & 7;
    int xcd = blockIdx.x & 7, jj = blockIdx.x >> 3;
    int wg = (xcd < r ? xcd * (q + 1) : r * (q + 1) + (xcd - r) * q) + jj;
    int row0 = (wg / NB) * TBM, col0 = (wg % NB) * TBN;

    int w = t >> 6, l = t & 63;
    int wr = w >> 1, wc = w & 1;
    f32x4 acc[FM][FN] = {};

    int srow = w * 8 + (l >> 3);                 // row within 32-row issue chunk
    int scs = ((l & 7) ^ (l >> 3)) * 8;          // source col in shorts (inverse swizzle)
    const unsigned short* ap[AISS];
    const unsigned short* bp[BISS];
    unsigned short* asd[AISS];
    unsigned short* bsd[BISS];
#pragma unroll
    for (int i = 0; i < AISS; i++) {
        ap[i] = A + (size_t)min(row0 + i * 32 + srow, M - 1) * K + scs;
        asd[i] = As + i * 2048 + w * 512;
    }
#pragma unroll
    for (int i = 0; i < BISS; i++) {
        bp[i] = B + (size_t)(col0 + i * 32 + srow) * K + scs;
        bsd[i] = Bs + i * 2048 + w * 512;
    }

    int rr = l & 15;
    int rb = (rr & 7) << 4;          // per-row byte XOR for ds_read
    int kb0 = (l >> 4) << 4;         // 0,16,32,48 byte within K-slice
    const char* Ab = (const char*)As;
    const char* Bb = (const char*)Bs;

#define GLD(src, dst) __builtin_amdgcn_global_load_lds( \
        (const __attribute__((address_space(1))) void*)(src), \
        (__attribute__((address_space(3))) void*)(dst), 16, 0, 0)

    for (int k0 = 0; k0 < K; k0 += 64) {
#pragma unroll
        for (int i = 0; i < AISS; i++) { GLD(ap[i], asd[i]); ap[i] += 64; }
#pragma unroll
        for (int i = 0; i < BISS; i++) { GLD(bp[i], bsd[i]); bp[i] += 64; }
        __syncthreads();

#pragma unroll
        for (int ks = 0; ks < 2; ks++) {
            int kb = ((ks << 6) | kb0) ^ rb;
            bf16x8 af[FM], bfv[FN];
#pragma unroll
            for (int mi = 0; mi < FM; mi++)
                af[mi] = *reinterpret_cast<const bf16x8*>(
                    Ab + (wr * (TBM / 2) + mi * 16 + rr) * 128 + kb);
#pragma unroll
            for (int ni = 0; ni < FN; ni++)
                bfv[ni] = *reinterpret_cast<const bf16x8*>(
                    Bb + (wc * (TBN / 2) + ni * 16 + rr) * 128 + kb);
#pragma unroll
            for (int mi = 0; mi < FM; mi++)
#pragma unroll
                for (int ni = 0; ni < FN; ni++)
                    acc[mi][ni] = __builtin_amdgcn_mfma_f32_16x16x32_bf16(
                        af[mi], bfv[ni], acc[mi][ni], 0, 0, 0);
        }
        __syncthreads();
    }
#undef GLD

    // C/D: col = lane&15, row = (lane>>4)*4 + j
    int c_l = l & 15, r_h = (l >> 4) * 4;
#pragma unroll
    for (int mi = 0; mi < FM; mi++)
#pragma unroll
        for (int ni = 0; ni < FN; ni++) {
            int gc = col0 + wc * (TBN / 2) + ni * 16 + c_l;
#pragma unroll
            for (int j = 0; j < 4; j++) {
                int gr = row0 + wr * (TBM / 2) + mi * 16 + r_h + j;
                if (gr < M) {
                    float v = acc[mi][ni][j];
                    if (bias) v += bias[gc];
                    if (Cf) Cf[(size_t)gr * N + gc] = v;
                    if (Cb) Cb[(size_t)gr * N + gc] = f2b(v);
                }
            }
        }
}

// ---- a_src/a_dst dots: wave-per-node. Lane l: head l>>4, 16 channels.
__global__ __launch_bounds__(256) void att_kernel(const unsigned short* __restrict__ hb,
                                                  const float* __restrict__ att_s,
                                                  const float* __restrict__ att_d,
                                                  float* __restrict__ aS, float* __restrict__ aD) {
    int node = blockIdx.x * 4 + (threadIdx.x >> 6);
    int l = threadIdx.x & 63;
    int head = l >> 4, qq = l & 15;
    const unsigned short* hrow = hb + (size_t)node * D1 + head * HID + qq * 16;
    bf16x8 h0 = *reinterpret_cast<const bf16x8*>(hrow);
    bf16x8 h1 = *reinterpret_cast<const bf16x8*>(hrow + 8);
    const float* asp = att_s + head * HID + qq * 16;
    const float* adp = att_d + head * HID + qq * 16;
    float ps = 0.f, pd = 0.f;
#pragma unroll
    for (int c = 0; c < 8; c++) {
        float hv = b2f((unsigned short)h0[c]);
        float hw = b2f((unsigned short)h1[c]);
        ps += hv * asp[c] + hw * asp[8 + c];
        pd += hv * adp[c] + hw * adp[8 + c];
    }
#pragma unroll
    for (int off = 1; off <= 8; off <<= 1) {
        ps += __shfl_xor(ps, off);
        pd += __shfl_xor(pd, off);
    }
    if (qq == 0) {
        aS[node * HEADS + head] = ps;
        aD[node * HEADS + head] = pd;
    }
}

// ---- aggregation: wave-per-node, barrier-free, no LDS (r6 best-known form).
__global__ __launch_bounds__(256) void agg_kernel(const unsigned short* __restrict__ hb,
                                                  const float* __restrict__ aS,
                                                  const float* __restrict__ aD,
                                                  const int* __restrict__ indptr,
                                                  const int* __restrict__ csr_src,
                                                  const float* __restrict__ bias,
                                                  unsigned short* __restrict__ outb) {
    int node = blockIdx.x * 4 + (threadIdx.x >> 6);
    int l = threadIdx.x & 63;
    int head = l >> 4;
    int beg = indptr[node];
    int deg = indptr[node + 1] - beg;
    float adst = aD[node * HEADS + head];
    const unsigned short* hp = hb + (size_t)l * 16;
    const int* cs = csr_src + beg;
    float acc[16];
#pragma unroll
    for (int c = 0; c < 16; c++) acc[c] = 0.f;
    float esum = 0.f;
    int dm = deg - 1;
    for (int j = 0; j < deg; j += 4) {
        int i0 = j, i1 = min(j + 1, dm), i2 = min(j + 2, dm), i3 = min(j + 3, dm);
        int s0 = cs[i0], s1 = cs[i1], s2 = cs[i2], s3 = cs[i3];
        const unsigned short* r0 = hp + (size_t)s0 * D1;
        const unsigned short* r1 = hp + (size_t)s1 * D1;
        const unsigned short* r2 = hp + (size_t)s2 * D1;
        const unsigned short* r3 = hp + (size_t)s3 * D1;
        bf16x8 r0a = *reinterpret_cast<const bf16x8*>(r0);
        bf16x8 r0b = *reinterpret_cast<const bf16x8*>(r0 + 8);
        bf16x8 r1a = *reinterpret_cast<const bf16x8*>(r1);
        bf16x8 r1b = *reinterpret_cast<const bf16x8*>(r1 + 8);
        bf16x8 r2a = *reinterpret_cast<const bf16x8*>(r2);
        bf16x8 r2b = *reinterpret_cast<const bf16x8*>(r2 + 8);
        bf16x8 r3a = *reinterpret_cast<const bf16x8*>(r3);
        bf16x8 r3b = *reinterpret_cast<const bf16x8*>(r3 + 8);
        float e0 = __expf(lrelu(aS[s0 * HEADS + head] + adst));
        float e1 = (j + 1 <= dm) ? __expf(lrelu(aS[s1 * HEADS + head] + adst)) : 0.f;
        float e2 = (j + 2 <= dm) ? __expf(lrelu(aS[s2 * HEADS + head] + adst)) : 0.f;
        float e3 = (j + 3 <= dm) ? __expf(lrelu(aS[s3 * HEADS + head] + adst)) : 0.f;
        esum += e0 + e1 + e2 + e3;
#pragma unroll
        for (int c = 0; c < 8; c++) {
            acc[c] += e0 * b2f((unsigned short)r0a[c]) + e1 * b2f((unsigned short)r1a[c])
                    + e2 * b2f((unsigned short)r2a[c]) + e3 * b2f((unsigned short)r3a[c]);
            acc[8 + c] += e0 * b2f((unsigned short)r0b[c]) + e1 * b2f((unsigned short)r1b[c])
                        + e2 * b2f((unsigned short)r2b[c]) + e3 * b2f((unsigned short)r3b[c]);
        }
    }
    float inv = 1.f / (esum + 1e-16f);
    const float* bp = bias + l * 16;
    bf16x8 o0, o1;
#pragma unroll
    for (int c = 0; c < 8; c++) {
        o0[c] = (short)f2b(fmaxf(acc[c] * inv + bp[c], 0.f));
        o1[c] = (short)f2b(fmaxf(acc[8 + c] * inv + bp[8 + c], 0.f));
    }
    unsigned short* op = outb + (size_t)node * D1 + l * 16;
    *reinterpret_cast<bf16x8*>(op) = o0;
    *reinterpret_cast<bf16x8*>(op + 8) = o1;
}

extern "C" void kernel_launch(void* const* d_in, const int* in_sizes, int n_in,
                              void* d_out, int out_size, void* d_ws, size_t ws_size,
                              hipStream_t stream) {
    const float* x   = (const float*)d_in[0];
    const void*  ei  = d_in[1];
    const float* W1  = (const float*)d_in[2];
    const float* as1 = (const float*)d_in[3];
    const float* ad1 = (const float*)d_in[4];
    const float* b1  = (const float*)d_in[5];
    const float* W2  = (const float*)d_in[6];
    const float* as2 = (const float*)d_in[7];
    const float* ad2 = (const float*)d_in[8];
    const float* b2  = (const float*)d_in[9];
    const float* fcW = (const float*)d_in[10];
    const float* fcb = (const float*)d_in[11];
    float* out = (float*)d_out;

    char* ws = (char*)d_ws;
    size_t o = 0;
    auto carve = [&](size_t bytes) -> char* {
        char* p = ws + o;
        o = (o + bytes + 255) & ~(size_t)255;
        return p;
    };
    unsigned short* xb   = (unsigned short*)carve((size_t)NN * IN_DIM * 2);
    unsigned short* hb   = (unsigned short*)carve((size_t)NN * D1 * 2);
    unsigned short* x2b  = (unsigned short*)carve((size_t)NN * D1 * 2);
    unsigned short* W1t  = (unsigned short*)carve((size_t)D1 * IN_DIM * 2);
    unsigned short* W2t  = (unsigned short*)carve((size_t)D1 * D1 * 2);
    unsigned short* fcWt = (unsigned short*)carve((size_t)OUT_DIM * D1 * 2);
    float* aS   = (float*)carve((size_t)NN * HEADS * 4);
    float* aD   = (float*)carve((size_t)NN * HEADS * 4);
    int* counts = (int*)carve((size_t)NN * 4);
    int* cursor = (int*)carve((size_t)NN * 4);
    int* indptr = (int*)carve((size_t)(NN + 1) * 4);
    int* csr_src= (int*)carve((size_t)NET * 4);
    int* flag   = (int*)carve(4);
    (void)ws_size; (void)in_sizes; (void)n_in; (void)out_size;

    // CSR build (dtype-agnostic edge loads)
    init_kernel<<<(NN + 255) / 256, 256, 0, stream>>>((const int*)ei, flag, counts, cursor);
    count_kernel<<<(NET + 255) / 256, 256, 0, stream>>>(ei, flag, counts);
    scan_kernel<<<1, 256, 0, stream>>>(counts, indptr);
    fill_kernel<<<(NET + 255) / 256, 256, 0, stream>>>(ei, flag, indptr, cursor, csr_src);

    // fused conversions (cvt + 3 transposes)
    prep_kernel<<<CVT_NB + TP1_NB + TP2_NB + TP3_NB, 256, 0, stream>>>(
        x, xb, W1, W1t, W2, W2t, fcW, fcWt);

    const int MB128 = (NN + 127) / 128;  // 79
    const int MB64  = (NN + 63) / 64;    // 157
    // layer 1
    gemmT<128, 64><<<MB128 * (D1 / 64), 256, 0, stream>>>(xb, W1t, nullptr, nullptr, hb,
                                                          NN, D1, IN_DIM, D1 / 64);
    att_kernel<<<NN / 4, 256, 0, stream>>>(hb, as1, ad1, aS, aD);
    agg_kernel<<<NN / 4, 256, 0, stream>>>(hb, aS, aD, indptr, csr_src, b1, x2b);
    // layer 2
    gemmT<128, 64><<<MB128 * (D1 / 64), 256, 0, stream>>>(x2b, W2t, nullptr, nullptr, hb,
                                                          NN, D1, D1, D1 / 64);
    att_kernel<<<NN / 4, 256, 0, stream>>>(hb, as2, ad2, aS, aD);
    agg_kernel<<<NN / 4, 256, 0, stream>>>(hb, aS, aD, indptr, csr_src, b2, x2b);
    // final fc (bias, f32 out)
    gemmT<64, 64><<<MB64 * (OUT_DIM / 64), 256, 0, stream>>>(x2b, fcWt, fcb, out, nullptr,
                                                             NN, OUT_DIM, D1, OUT_DIM / 64);
}

// Round 11
// 239.914 us; speedup vs baseline: 1.2298x; 1.0042x over previous
//
#include <hip/hip_runtime.h>
#include <hip/hip_bf16.h>

#define NN 10000
#define NE 160000
#define NET 170000   // edges + self loops
#define IN_DIM 512
#define D1 1024      // HEADS*HID
#define HEADS 4
#define HID 256
#define OUT_DIM 512
#define NEG_SLOPE 0.2f

typedef __attribute__((ext_vector_type(8))) short bf16x8;
typedef __attribute__((ext_vector_type(4))) float f32x4;

__device__ inline float b2f(unsigned short b) {
    union { unsigned u; float f; } x; x.u = ((unsigned)b) << 16; return x.f;
}
__device__ inline unsigned short f2b(float f) {
    union { float f; unsigned u; } x; x.f = f;
    unsigned u = x.u;
    unsigned r = u + 0x7FFFu + ((u >> 16) & 1u);
    return (unsigned short)(r >> 16);
}
__device__ inline float lrelu(float v) { return v > 0.f ? v : NEG_SLOPE * v; }

__device__ inline void load_edge(const void* ei, int f64, int e, int& s, int& d) {
    if (f64) {
        const long long* p = (const long long*)ei;
        s = (int)p[e]; d = (int)p[NE + e];
    } else {
        const int* p = (const int*)ei;
        s = p[e]; d = p[NE + e];
    }
}

__global__ void count_kernel(const void* ei, const int* flag, int* counts) {
    int e = blockIdx.x * blockDim.x + threadIdx.x;
    if (e >= NET) return;
    int s, d;
    if (e < NE) load_edge(ei, *flag, e, s, d);
    else d = e - NE;
    atomicAdd(&counts[d], 1);
}

__global__ __launch_bounds__(256) void scan_kernel(const int* counts, int* indptr) {
    __shared__ int part[256];
    int t = threadIdx.x;
    int base = t * 40;
    int local[40];
    int sum = 0;
#pragma unroll
    for (int k = 0; k < 40; k++) {
        int i = base + k;
        int c = (i < NN) ? counts[i] : 0;
        local[k] = sum;
        sum += c;
    }
    part[t] = sum;
    __syncthreads();
    for (int off = 1; off < 256; off <<= 1) {
        int v = (t >= off) ? part[t - off] : 0;
        __syncthreads();
        part[t] += v;
        __syncthreads();
    }
    int excl = part[t] - sum;
#pragma unroll
    for (int k = 0; k < 40; k++) {
        int i = base + k;
        if (i < NN) indptr[i] = excl + local[k];
    }
    if (t == 255) indptr[NN] = part[255];
}

__global__ void fill_kernel(const void* ei, const int* flag, const int* indptr,
                            int* cursor, int* csr_src) {
    int e = blockIdx.x * blockDim.x + threadIdx.x;
    if (e >= NET) return;
    int s, d;
    if (e < NE) load_edge(ei, *flag, e, s, d);
    else { s = e - NE; d = s; }
    int pos = indptr[d] + atomicAdd(&cursor[d], 1);
    csr_src[pos] = s;
}

// ---- setup: init (zero counts/cursor + dtype detect) fused with
// x->bf16 convert + 3 weight transposes (sectioned 1D grid)
__device__ void tpose_tile(const float* __restrict__ in, unsigned short* __restrict__ out,
                           int R, int C, int bx, int by) {
    __shared__ float tile[32][33];
    int tx = threadIdx.x & 31, ty = threadIdx.x >> 5;
    int c = bx * 32 + tx;
#pragma unroll
    for (int r0 = 0; r0 < 32; r0 += 8) {
        int r = by * 32 + ty + r0;
        tile[ty + r0][tx] = in[(size_t)r * C + c];
    }
    __syncthreads();
    int oc = by * 32 + tx;
#pragma unroll
    for (int r0 = 0; r0 < 32; r0 += 8) {
        int orow = bx * 32 + ty + r0;
        out[(size_t)orow * R + oc] = f2b(tile[tx][ty + r0]);
    }
}

#define INIT_NB 40    // ceil(NN/256)
#define CVT_NB 5000   // NN*IN_DIM/4/256
#define TP1_NB 512    // (D1/32)*(IN_DIM/32)
#define TP2_NB 1024   // (D1/32)*(D1/32)
#define TP3_NB 512    // (OUT_DIM/32)*(D1/32)
__global__ __launch_bounds__(256) void setup_kernel(
    const int* ei32, int* flag, int* counts, int* cursor,
    const float* __restrict__ x, unsigned short* __restrict__ xb,
    const float* __restrict__ W1, unsigned short* __restrict__ W1t,
    const float* __restrict__ W2, unsigned short* __restrict__ W2t,
    const float* __restrict__ fcW, unsigned short* __restrict__ fcWt) {
    int b = blockIdx.x;
    if (b < INIT_NB) {
        int i = b * 256 + threadIdx.x;
        if (i < NN) { counts[i] = 0; cursor[i] = 0; }
        if (b == 0) {
            __shared__ int nz;
            if (threadIdx.x == 0) nz = 0;
            __syncthreads();
            int acc = 0;
            for (int k = threadIdx.x; k < 500; k += 256) acc |= ei32[2 * k + 1];
            if (acc) atomicOr(&nz, 1);
            __syncthreads();
            if (threadIdx.x == 0) flag[0] = (nz == 0) ? 1 : 0;
        }
        return;
    }
    b -= INIT_NB;
    if (b < CVT_NB) {
        int i = b * 256 + threadIdx.x;
        float4 v = reinterpret_cast<const float4*>(x)[i];
        ushort4 o;
        o.x = f2b(v.x); o.y = f2b(v.y); o.z = f2b(v.z); o.w = f2b(v.w);
        reinterpret_cast<ushort4*>(xb)[i] = o;
        return;
    }
    b -= CVT_NB;
    if (b < TP1_NB) { tpose_tile(W1, W1t, IN_DIM, D1, b & 31, b >> 5); return; }
    b -= TP1_NB;
    if (b < TP2_NB) { tpose_tile(W2, W2t, D1, D1, b & 31, b >> 5); return; }
    b -= TP2_NB;
    tpose_tile(fcW, fcWt, D1, OUT_DIM, b & 15, b >> 4);
}

// ---- C[M][N] = A[M][K](bf16) @ B[N][K](bf16)^T ; templated tile TBMxTBN,
// BK=64, 4 waves (2x2), global_load_lds width 16, XOR-swizzled LDS,
// bijective XCD-aware block swizzle, DOUBLE-BUFFERED LDS (2-phase: issue
// next tile's loads before computing current -> HBM/L2 latency hides
// under MFMA; one barrier per K-step).
template<int TBM, int TBN>
__global__ __launch_bounds__(256) void gemmT(
    const unsigned short* __restrict__ A, const unsigned short* __restrict__ B,
    const float* __restrict__ bias, float* __restrict__ Cf, unsigned short* __restrict__ Cb,
    int M, int N, int K, int NB) {
    constexpr int FM = TBM / 32;    // fragments per wave (M)
    constexpr int FN = TBN / 32;    // fragments per wave (N)
    constexpr int AISS = TBM / 32;  // 32-row staging issues for A
    constexpr int BISS = TBN / 32;
    constexpr int ABUF = TBM * 64;  // elements per buffer
    constexpr int BBUF = TBN * 64;
    __shared__ __align__(16) unsigned short As[2 * ABUF];
    __shared__ __align__(16) unsigned short Bs[2 * BBUF];
    int t = threadIdx.x;
    int nwg = gridDim.x;
    int q = nwg >> 3, r = nwg & 7;
    int xcd = blockIdx.x & 7, jj = blockIdx.x >> 3;
    int wg = (xcd < r ? xcd * (q + 1) : r * (q + 1) + (xcd - r) * q) + jj;
    int row0 = (wg / NB) * TBM, col0 = (wg % NB) * TBN;

    int w = t >> 6, l = t & 63;
    int wr = w >> 1, wc = w & 1;
    f32x4 acc[FM][FN] = {};

    int srow = w * 8 + (l >> 3);                 // row within 32-row issue chunk
    int scs = ((l & 7) ^ (l >> 3)) * 8;          // source col in shorts (inverse swizzle)
    const unsigned short* ap[AISS];
    const unsigned short* bp[BISS];
#pragma unroll
    for (int i = 0; i < AISS; i++)
        ap[i] = A + (size_t)min(row0 + i * 32 + srow, M - 1) * K + scs;
#pragma unroll
    for (int i = 0; i < BISS; i++)
        bp[i] = B + (size_t)(col0 + i * 32 + srow) * K + scs;

    int rr = l & 15;
    int rb = (rr & 7) << 4;          // per-row byte XOR for ds_read
    int kb0 = (l >> 4) << 4;         // 0,16,32,48 byte within K-slice
    int c_l = l & 15, r_h = (l >> 4) * 4;

#define GLD(src, dst) __builtin_amdgcn_global_load_lds( \
        (const __attribute__((address_space(1))) void*)(src), \
        (__attribute__((address_space(3))) void*)(dst), 16, 0, 0)

    // prologue: stage K-tile 0 into buffer 0
#pragma unroll
    for (int i = 0; i < AISS; i++) { GLD(ap[i], As + i * 2048 + w * 512); ap[i] += 64; }
#pragma unroll
    for (int i = 0; i < BISS; i++) { GLD(bp[i], Bs + i * 2048 + w * 512); bp[i] += 64; }
    __syncthreads();

    int cur = 0;
    for (int k0 = 0; k0 < K; k0 += 64) {
        int nxt = cur ^ 1;
        if (k0 + 64 < K) {   // issue next tile's loads; they fly during MFMA below
#pragma unroll
            for (int i = 0; i < AISS; i++) {
                GLD(ap[i], As + nxt * ABUF + i * 2048 + w * 512);
                ap[i] += 64;
            }
#pragma unroll
            for (int i = 0; i < BISS; i++) {
                GLD(bp[i], Bs + nxt * BBUF + i * 2048 + w * 512);
                bp[i] += 64;
            }
        }
        const char* Ab = (const char*)(As + cur * ABUF);
        const char* Bb = (const char*)(Bs + cur * BBUF);
#pragma unroll
        for (int ks = 0; ks < 2; ks++) {
            int kb = ((ks << 6) | kb0) ^ rb;
            bf16x8 af[FM], bfv[FN];
#pragma unroll
            for (int mi = 0; mi < FM; mi++)
                af[mi] = *reinterpret_cast<const bf16x8*>(
                    Ab + (wr * (TBM / 2) + mi * 16 + rr) * 128 + kb);
#pragma unroll
            for (int ni = 0; ni < FN; ni++)
                bfv[ni] = *reinterpret_cast<const bf16x8*>(
                    Bb + (wc * (TBN / 2) + ni * 16 + rr) * 128 + kb);
#pragma unroll
            for (int mi = 0; mi < FM; mi++)
#pragma unroll
                for (int ni = 0; ni < FN; ni++)
                    acc[mi][ni] = __builtin_amdgcn_mfma_f32_16x16x32_bf16(
                        af[mi], bfv[ni], acc[mi][ni], 0, 0, 0);
        }
        __syncthreads();   // drains next-tile loads (issued pre-MFMA) + guards swap
        cur = nxt;
    }
#undef GLD

    // C/D: col = lane&15, row = (lane>>4)*4 + j
#pragma unroll
    for (int mi = 0; mi < FM; mi++)
#pragma unroll
        for (int ni = 0; ni < FN; ni++) {
            int gc = col0 + wc * (TBN / 2) + ni * 16 + c_l;
#pragma unroll
            for (int j = 0; j < 4; j++) {
                int gr = row0 + wr * (TBM / 2) + mi * 16 + r_h + j;
                if (gr < M) {
                    float v = acc[mi][ni][j];
                    if (bias) v += bias[gc];
                    if (Cf) Cf[(size_t)gr * N + gc] = v;
                    if (Cb) Cb[(size_t)gr * N + gc] = f2b(v);
                }
            }
        }
}

// ---- a_src/a_dst dots: wave-per-node. Lane l: head l>>4, 16 channels.
__global__ __launch_bounds__(256) void att_kernel(const unsigned short* __restrict__ hb,
                                                  const float* __restrict__ att_s,
                                                  const float* __restrict__ att_d,
                                                  float* __restrict__ aS, float* __restrict__ aD) {
    int node = blockIdx.x * 4 + (threadIdx.x >> 6);
    int l = threadIdx.x & 63;
    int head = l >> 4, qq = l & 15;
    const unsigned short* hrow = hb + (size_t)node * D1 + head * HID + qq * 16;
    bf16x8 h0 = *reinterpret_cast<const bf16x8*>(hrow);
    bf16x8 h1 = *reinterpret_cast<const bf16x8*>(hrow + 8);
    const float* asp = att_s + head * HID + qq * 16;
    const float* adp = att_d + head * HID + qq * 16;
    float ps = 0.f, pd = 0.f;
#pragma unroll
    for (int c = 0; c < 8; c++) {
        float hv = b2f((unsigned short)h0[c]);
        float hw = b2f((unsigned short)h1[c]);
        ps += hv * asp[c] + hw * asp[8 + c];
        pd += hv * adp[c] + hw * adp[8 + c];
    }
#pragma unroll
    for (int off = 1; off <= 8; off <<= 1) {
        ps += __shfl_xor(ps, off);
        pd += __shfl_xor(pd, off);
    }
    if (qq == 0) {
        aS[node * HEADS + head] = ps;
        aD[node * HEADS + head] = pd;
    }
}

// ---- aggregation: wave-per-node, barrier-free, no LDS (r6 best-known form;
// five alternative structures all converge at ~51us -> per-CU gather-rate
// hardware floor for random 2KB row gathers).
__global__ __launch_bounds__(256) void agg_kernel(const unsigned short* __restrict__ hb,
                                                  const float* __restrict__ aS,
                                                  const float* __restrict__ aD,
                                                  const int* __restrict__ indptr,
                                                  const int* __restrict__ csr_src,
                                                  const float* __restrict__ bias,
                                                  unsigned short* __restrict__ outb) {
    int node = blockIdx.x * 4 + (threadIdx.x >> 6);
    int l = threadIdx.x & 63;
    int head = l >> 4;
    int beg = indptr[node];
    int deg = indptr[node + 1] - beg;
    float adst = aD[node * HEADS + head];
    const unsigned short* hp = hb + (size_t)l * 16;
    const int* cs = csr_src + beg;
    float acc[16];
#pragma unroll
    for (int c = 0; c < 16; c++) acc[c] = 0.f;
    float esum = 0.f;
    int dm = deg - 1;
    for (int j = 0; j < deg; j += 4) {
        int i0 = j, i1 = min(j + 1, dm), i2 = min(j + 2, dm), i3 = min(j + 3, dm);
        int s0 = cs[i0], s1 = cs[i1], s2 = cs[i2], s3 = cs[i3];
        const unsigned short* r0 = hp + (size_t)s0 * D1;
        const unsigned short* r1 = hp + (size_t)s1 * D1;
        const unsigned short* r2 = hp + (size_t)s2 * D1;
        const unsigned short* r3 = hp + (size_t)s3 * D1;
        bf16x8 r0a = *reinterpret_cast<const bf16x8*>(r0);
        bf16x8 r0b = *reinterpret_cast<const bf16x8*>(r0 + 8);
        bf16x8 r1a = *reinterpret_cast<const bf16x8*>(r1);
        bf16x8 r1b = *reinterpret_cast<const bf16x8*>(r1 + 8);
        bf16x8 r2a = *reinterpret_cast<const bf16x8*>(r2);
        bf16x8 r2b = *reinterpret_cast<const bf16x8*>(r2 + 8);
        bf16x8 r3a = *reinterpret_cast<const bf16x8*>(r3);
        bf16x8 r3b = *reinterpret_cast<const bf16x8*>(r3 + 8);
        float e0 = __expf(lrelu(aS[s0 * HEADS + head] + adst));
        float e1 = (j + 1 <= dm) ? __expf(lrelu(aS[s1 * HEADS + head] + adst)) : 0.f;
        float e2 = (j + 2 <= dm) ? __expf(lrelu(aS[s2 * HEADS + head] + adst)) : 0.f;
        float e3 = (j + 3 <= dm) ? __expf(lrelu(aS[s3 * HEADS + head] + adst)) : 0.f;
        esum += e0 + e1 + e2 + e3;
#pragma unroll
        for (int c = 0; c < 8; c++) {
            acc[c] += e0 * b2f((unsigned short)r0a[c]) + e1 * b2f((unsigned short)r1a[c])
                    + e2 * b2f((unsigned short)r2a[c]) + e3 * b2f((unsigned short)r3a[c]);
            acc[8 + c] += e0 * b2f((unsigned short)r0b[c]) + e1 * b2f((unsigned short)r1b[c])
                        + e2 * b2f((unsigned short)r2b[c]) + e3 * b2f((unsigned short)r3b[c]);
        }
    }
    float inv = 1.f / (esum + 1e-16f);
    const float* bp = bias + l * 16;
    bf16x8 o0, o1;
#pragma unroll
    for (int c = 0; c < 8; c++) {
        o0[c] = (short)f2b(fmaxf(acc[c] * inv + bp[c], 0.f));
        o1[c] = (short)f2b(fmaxf(acc[8 + c] * inv + bp[8 + c], 0.f));
    }
    unsigned short* op = outb + (size_t)node * D1 + l * 16;
    *reinterpret_cast<bf16x8*>(op) = o0;
    *reinterpret_cast<bf16x8*>(op + 8) = o1;
}

extern "C" void kernel_launch(void* const* d_in, const int* in_sizes, int n_in,
                              void* d_out, int out_size, void* d_ws, size_t ws_size,
                              hipStream_t stream) {
    const float* x   = (const float*)d_in[0];
    const void*  ei  = d_in[1];
    const float* W1  = (const float*)d_in[2];
    const float* as1 = (const float*)d_in[3];
    const float* ad1 = (const float*)d_in[4];
    const float* b1  = (const float*)d_in[5];
    const float* W2  = (const float*)d_in[6];
    const float* as2 = (const float*)d_in[7];
    const float* ad2 = (const float*)d_in[8];
    const float* b2  = (const float*)d_in[9];
    const float* fcW = (const float*)d_in[10];
    const float* fcb = (const float*)d_in[11];
    float* out = (float*)d_out;

    char* ws = (char*)d_ws;
    size_t o = 0;
    auto carve = [&](size_t bytes) -> char* {
        char* p = ws + o;
        o = (o + bytes + 255) & ~(size_t)255;
        return p;
    };
    unsigned short* xb   = (unsigned short*)carve((size_t)NN * IN_DIM * 2);
    unsigned short* hb   = (unsigned short*)carve((size_t)NN * D1 * 2);
    unsigned short* x2b  = (unsigned short*)carve((size_t)NN * D1 * 2);
    unsigned short* W1t  = (unsigned short*)carve((size_t)D1 * IN_DIM * 2);
    unsigned short* W2t  = (unsigned short*)carve((size_t)D1 * D1 * 2);
    unsigned short* fcWt = (unsigned short*)carve((size_t)OUT_DIM * D1 * 2);
    float* aS   = (float*)carve((size_t)NN * HEADS * 4);
    float* aD   = (float*)carve((size_t)NN * HEADS * 4);
    int* counts = (int*)carve((size_t)NN * 4);
    int* cursor = (int*)carve((size_t)NN * 4);
    int* indptr = (int*)carve((size_t)(NN + 1) * 4);
    int* csr_src= (int*)carve((size_t)NET * 4);
    int* flag   = (int*)carve(4);
    (void)ws_size; (void)in_sizes; (void)n_in; (void)out_size;

    // setup: init (counts/cursor/dtype) + cvt + 3 transposes, one kernel
    setup_kernel<<<INIT_NB + CVT_NB + TP1_NB + TP2_NB + TP3_NB, 256, 0, stream>>>(
        (const int*)ei, flag, counts, cursor, x, xb, W1, W1t, W2, W2t, fcW, fcWt);
    count_kernel<<<(NET + 255) / 256, 256, 0, stream>>>(ei, flag, counts);
    scan_kernel<<<1, 256, 0, stream>>>(counts, indptr);
    fill_kernel<<<(NET + 255) / 256, 256, 0, stream>>>(ei, flag, indptr, cursor, csr_src);

    const int MB128 = (NN + 127) / 128;  // 79
    const int MB64  = (NN + 63) / 64;    // 157
    // layer 1
    gemmT<128, 64><<<MB128 * (D1 / 64), 256, 0, stream>>>(xb, W1t, nullptr, nullptr, hb,
                                                          NN, D1, IN_DIM, D1 / 64);
    att_kernel<<<NN / 4, 256, 0, stream>>>(hb, as1, ad1, aS, aD);
    agg_kernel<<<NN / 4, 256, 0, stream>>>(hb, aS, aD, indptr, csr_src, b1, x2b);
    // layer 2
    gemmT<128, 64><<<MB128 * (D1 / 64), 256, 0, stream>>>(x2b, W2t, nullptr, nullptr, hb,
                                                          NN, D1, D1, D1 / 64);
    att_kernel<<<NN / 4, 256, 0, stream>>>(hb, as2, ad2, aS, aD);
    agg_kernel<<<NN / 4, 256, 0, stream>>>(hb, aS, aD, indptr, csr_src, b2, x2b);
    // final fc (bias, f32 out)
    gemmT<64, 64><<<MB64 * (OUT_DIM / 64), 256, 0, stream>>>(x2b, fcWt, fcb, out, nullptr,
                                                             NN, OUT_DIM, D1, OUT_DIM / 64);
}

// Round 12
// 228.909 us; speedup vs baseline: 1.2890x; 1.0481x over previous
//
#include <hip/hip_runtime.h>
#include <hip/hip_bf16.h>

#define NN 10000
#define NE 160000
#define NET 170000   // edges + self loops
#define IN_DIM 512
#define D1 1024      // HEADS*HID
#define HEADS 4
#define HID 256
#define OUT_DIM 512
#define NEG_SLOPE 0.2f

typedef __attribute__((ext_vector_type(8))) short bf16x8;
typedef __attribute__((ext_vector_type(4))) float f32x4;

__device__ inline float b2f(unsigned short b) {
    union { unsigned u; float f; } x; x.u = ((unsigned)b) << 16; return x.f;
}
__device__ inline unsigned short f2b(float f) {
    union { float f; unsigned u; } x; x.f = f;
    unsigned u = x.u;
    unsigned r = u + 0x7FFFu + ((u >> 16) & 1u);
    return (unsigned short)(r >> 16);
}
__device__ inline float lrelu(float v) { return v > 0.f ? v : NEG_SLOPE * v; }

// int64 edge_index detect, per-thread inline: high dwords of first 16 values
// are all zero iff int64 (node ids < 2^31; P(16 random ids all 0) ~ 0).
__device__ inline bool is64(const int* ei32) {
    int acc = 0;
#pragma unroll
    for (int k = 0; k < 16; k++) acc |= ei32[2 * k + 1];
    return acc == 0;
}

__device__ inline void load_edge(const void* ei, bool f64, int e, int& s, int& d) {
    if (f64) {
        const long long* p = (const long long*)ei;
        s = (int)p[e]; d = (int)p[NE + e];
    } else {
        const int* p = (const int*)ei;
        s = p[e]; d = p[NE + e];
    }
}

// ---- zero counts/cursor (must precede count section of setup)
__global__ void zero_kernel(int* counts, int* cursor) {
    int i = blockIdx.x * blockDim.x + threadIdx.x;
    if (i < NN) { counts[i] = 0; cursor[i] = 0; }
}

// ---- scan body (prefix sum of counts -> indptr), one 256-thread block
__device__ void scan_dev(const int* counts, int* indptr) {
    __shared__ int part[256];
    int t = threadIdx.x;
    int base = t * 40;
    int local[40];
    int sum = 0;
#pragma unroll
    for (int k = 0; k < 40; k++) {
        int i = base + k;
        int c = (i < NN) ? counts[i] : 0;
        local[k] = sum;
        sum += c;
    }
    part[t] = sum;
    __syncthreads();
    for (int off = 1; off < 256; off <<= 1) {
        int v = (t >= off) ? part[t - off] : 0;
        __syncthreads();
        part[t] += v;
        __syncthreads();
    }
    int excl = part[t] - sum;
#pragma unroll
    for (int k = 0; k < 40; k++) {
        int i = base + k;
        if (i < NN) indptr[i] = excl + local[k];
    }
    if (t == 255) indptr[NN] = part[255];
}

// ---- setup: x->bf16 convert + 3 weight transposes + COUNT section
__device__ void tpose_tile(const float* __restrict__ in, unsigned short* __restrict__ out,
                           int R, int C, int bx, int by) {
    __shared__ float tile[32][33];
    int tx = threadIdx.x & 31, ty = threadIdx.x >> 5;
    int c = bx * 32 + tx;
#pragma unroll
    for (int r0 = 0; r0 < 32; r0 += 8) {
        int r = by * 32 + ty + r0;
        tile[ty + r0][tx] = in[(size_t)r * C + c];
    }
    __syncthreads();
    int oc = by * 32 + tx;
#pragma unroll
    for (int r0 = 0; r0 < 32; r0 += 8) {
        int orow = bx * 32 + ty + r0;
        out[(size_t)orow * R + oc] = f2b(tile[tx][ty + r0]);
    }
}

#define CVT_NB 5000   // NN*IN_DIM/4/256
#define TP1_NB 512    // (D1/32)*(IN_DIM/32)
#define TP2_NB 1024   // (D1/32)*(D1/32)
#define TP3_NB 512    // (OUT_DIM/32)*(D1/32)
#define CNT_NB 665    // ceil(NET/256)
__global__ __launch_bounds__(256) void setup_kernel(
    const void* ei, int* counts,
    const float* __restrict__ x, unsigned short* __restrict__ xb,
    const float* __restrict__ W1, unsigned short* __restrict__ W1t,
    const float* __restrict__ W2, unsigned short* __restrict__ W2t,
    const float* __restrict__ fcW, unsigned short* __restrict__ fcWt) {
    int b = blockIdx.x;
    if (b < CVT_NB) {
        int i = b * 256 + threadIdx.x;
        float4 v = reinterpret_cast<const float4*>(x)[i];
        ushort4 o;
        o.x = f2b(v.x); o.y = f2b(v.y); o.z = f2b(v.z); o.w = f2b(v.w);
        reinterpret_cast<ushort4*>(xb)[i] = o;
        return;
    }
    b -= CVT_NB;
    if (b < TP1_NB) { tpose_tile(W1, W1t, IN_DIM, D1, b & 31, b >> 5); return; }
    b -= TP1_NB;
    if (b < TP2_NB) { tpose_tile(W2, W2t, D1, D1, b & 31, b >> 5); return; }
    b -= TP2_NB;
    if (b < TP3_NB) { tpose_tile(fcW, fcWt, D1, OUT_DIM, b & 15, b >> 4); return; }
    b -= TP3_NB;
    // count section
    int e = b * 256 + threadIdx.x;
    if (e >= NET) return;
    bool f64 = is64((const int*)ei);
    int s, d;
    if (e < NE) load_edge(ei, f64, e, s, d);
    else d = e - NE;
    atomicAdd(&counts[d], 1);
}

// ---- C[M][N] = A[M][K](bf16) @ B[N][K](bf16)^T ; templated tile TBMxTBN,
// BK=64, 4 waves (2x2), global_load_lds width 16, XOR-swizzled LDS,
// bijective XCD-aware block swizzle (NWG param), double-buffered LDS.
// Blocks with blockIdx >= NWG run the CSR scan instead (fused launch).
template<int TBM, int TBN>
__global__ __launch_bounds__(256) void gemmT(
    const unsigned short* __restrict__ A, const unsigned short* __restrict__ B,
    const float* __restrict__ bias, float* __restrict__ Cf, unsigned short* __restrict__ Cb,
    int M, int N, int K, int NB, int NWG,
    const int* __restrict__ sc_counts, int* __restrict__ sc_indptr) {
    if ((int)blockIdx.x >= NWG) { scan_dev(sc_counts, sc_indptr); return; }
    constexpr int FM = TBM / 32;
    constexpr int FN = TBN / 32;
    constexpr int AISS = TBM / 32;
    constexpr int BISS = TBN / 32;
    constexpr int ABUF = TBM * 64;
    constexpr int BBUF = TBN * 64;
    __shared__ __align__(16) unsigned short As[2 * ABUF];
    __shared__ __align__(16) unsigned short Bs[2 * BBUF];
    int t = threadIdx.x;
    int q = NWG >> 3, r = NWG & 7;
    int xcd = blockIdx.x & 7, jj = blockIdx.x >> 3;
    int wg = (xcd < r ? xcd * (q + 1) : r * (q + 1) + (xcd - r) * q) + jj;
    int row0 = (wg / NB) * TBM, col0 = (wg % NB) * TBN;

    int w = t >> 6, l = t & 63;
    int wr = w >> 1, wc = w & 1;
    f32x4 acc[FM][FN] = {};

    int srow = w * 8 + (l >> 3);
    int scs = ((l & 7) ^ (l >> 3)) * 8;          // inverse-swizzled source col
    const unsigned short* ap[AISS];
    const unsigned short* bp[BISS];
#pragma unroll
    for (int i = 0; i < AISS; i++)
        ap[i] = A + (size_t)min(row0 + i * 32 + srow, M - 1) * K + scs;
#pragma unroll
    for (int i = 0; i < BISS; i++)
        bp[i] = B + (size_t)(col0 + i * 32 + srow) * K + scs;

    int rr = l & 15;
    int rb = (rr & 7) << 4;
    int kb0 = (l >> 4) << 4;
    int c_l = l & 15, r_h = (l >> 4) * 4;

#define GLD(src, dst) __builtin_amdgcn_global_load_lds( \
        (const __attribute__((address_space(1))) void*)(src), \
        (__attribute__((address_space(3))) void*)(dst), 16, 0, 0)

#pragma unroll
    for (int i = 0; i < AISS; i++) { GLD(ap[i], As + i * 2048 + w * 512); ap[i] += 64; }
#pragma unroll
    for (int i = 0; i < BISS; i++) { GLD(bp[i], Bs + i * 2048 + w * 512); bp[i] += 64; }
    __syncthreads();

    int cur = 0;
    for (int k0 = 0; k0 < K; k0 += 64) {
        int nxt = cur ^ 1;
        if (k0 + 64 < K) {
#pragma unroll
            for (int i = 0; i < AISS; i++) {
                GLD(ap[i], As + nxt * ABUF + i * 2048 + w * 512);
                ap[i] += 64;
            }
#pragma unroll
            for (int i = 0; i < BISS; i++) {
                GLD(bp[i], Bs + nxt * BBUF + i * 2048 + w * 512);
                bp[i] += 64;
            }
        }
        const char* Ab = (const char*)(As + cur * ABUF);
        const char* Bb = (const char*)(Bs + cur * BBUF);
#pragma unroll
        for (int ks = 0; ks < 2; ks++) {
            int kb = ((ks << 6) | kb0) ^ rb;
            bf16x8 af[FM], bfv[FN];
#pragma unroll
            for (int mi = 0; mi < FM; mi++)
                af[mi] = *reinterpret_cast<const bf16x8*>(
                    Ab + (wr * (TBM / 2) + mi * 16 + rr) * 128 + kb);
#pragma unroll
            for (int ni = 0; ni < FN; ni++)
                bfv[ni] = *reinterpret_cast<const bf16x8*>(
                    Bb + (wc * (TBN / 2) + ni * 16 + rr) * 128 + kb);
#pragma unroll
            for (int mi = 0; mi < FM; mi++)
#pragma unroll
                for (int ni = 0; ni < FN; ni++)
                    acc[mi][ni] = __builtin_amdgcn_mfma_f32_16x16x32_bf16(
                        af[mi], bfv[ni], acc[mi][ni], 0, 0, 0);
        }
        __syncthreads();
        cur = nxt;
    }
#undef GLD

    // C/D: col = lane&15, row = (lane>>4)*4 + j
#pragma unroll
    for (int mi = 0; mi < FM; mi++)
#pragma unroll
        for (int ni = 0; ni < FN; ni++) {
            int gc = col0 + wc * (TBN / 2) + ni * 16 + c_l;
#pragma unroll
            for (int j = 0; j < 4; j++) {
                int gr = row0 + wr * (TBM / 2) + mi * 16 + r_h + j;
                if (gr < M) {
                    float v = acc[mi][ni][j];
                    if (bias) v += bias[gc];
                    if (Cf) Cf[(size_t)gr * N + gc] = v;
                    if (Cb) Cb[(size_t)gr * N + gc] = f2b(v);
                }
            }
        }
}

// ---- att dots (wave-per-node) + fused CSR fill section (blocks >= NATT)
__global__ __launch_bounds__(256) void att_fill_kernel(
    const unsigned short* __restrict__ hb,
    const float* __restrict__ att_s, const float* __restrict__ att_d,
    float* __restrict__ aS, float* __restrict__ aD,
    const void* ei, const int* __restrict__ indptr,
    int* __restrict__ cursor, int* __restrict__ csr_src, int NATT) {
    if ((int)blockIdx.x >= NATT) {
        int e = ((int)blockIdx.x - NATT) * 256 + threadIdx.x;
        if (e >= NET) return;
        bool f64 = is64((const int*)ei);
        int s, d;
        if (e < NE) load_edge(ei, f64, e, s, d);
        else { s = e - NE; d = s; }
        int pos = indptr[d] + atomicAdd(&cursor[d], 1);
        csr_src[pos] = s;
        return;
    }
    int node = blockIdx.x * 4 + (threadIdx.x >> 6);
    int l = threadIdx.x & 63;
    int head = l >> 4, qq = l & 15;
    const unsigned short* hrow = hb + (size_t)node * D1 + head * HID + qq * 16;
    bf16x8 h0 = *reinterpret_cast<const bf16x8*>(hrow);
    bf16x8 h1 = *reinterpret_cast<const bf16x8*>(hrow + 8);
    const float* asp = att_s + head * HID + qq * 16;
    const float* adp = att_d + head * HID + qq * 16;
    float ps = 0.f, pd = 0.f;
#pragma unroll
    for (int c = 0; c < 8; c++) {
        float hv = b2f((unsigned short)h0[c]);
        float hw = b2f((unsigned short)h1[c]);
        ps += hv * asp[c] + hw * asp[8 + c];
        pd += hv * adp[c] + hw * adp[8 + c];
    }
#pragma unroll
    for (int off = 1; off <= 8; off <<= 1) {
        ps += __shfl_xor(ps, off);
        pd += __shfl_xor(pd, off);
    }
    if (qq == 0) {
        aS[node * HEADS + head] = ps;
        aD[node * HEADS + head] = pd;
    }
}

// ---- aggregation: wave-per-node, barrier-free, no LDS (best-known form;
// six structures converge at ~51us: per-CU outstanding-line (MSHR) floor
// for random 2KB row gathers -> treated as hardware wall).
__global__ __launch_bounds__(256) void agg_kernel(const unsigned short* __restrict__ hb,
                                                  const float* __restrict__ aS,
                                                  const float* __restrict__ aD,
                                                  const int* __restrict__ indptr,
                                                  const int* __restrict__ csr_src,
                                                  const float* __restrict__ bias,
                                                  unsigned short* __restrict__ outb) {
    int node = blockIdx.x * 4 + (threadIdx.x >> 6);
    int l = threadIdx.x & 63;
    int head = l >> 4;
    int beg = indptr[node];
    int deg = indptr[node + 1] - beg;
    float adst = aD[node * HEADS + head];
    const unsigned short* hp = hb + (size_t)l * 16;
    const int* cs = csr_src + beg;
    float acc[16];
#pragma unroll
    for (int c = 0; c < 16; c++) acc[c] = 0.f;
    float esum = 0.f;
    int dm = deg - 1;
    for (int j = 0; j < deg; j += 4) {
        int i0 = j, i1 = min(j + 1, dm), i2 = min(j + 2, dm), i3 = min(j + 3, dm);
        int s0 = cs[i0], s1 = cs[i1], s2 = cs[i2], s3 = cs[i3];
        const unsigned short* r0 = hp + (size_t)s0 * D1;
        const unsigned short* r1 = hp + (size_t)s1 * D1;
        const unsigned short* r2 = hp + (size_t)s2 * D1;
        const unsigned short* r3 = hp + (size_t)s3 * D1;
        bf16x8 r0a = *reinterpret_cast<const bf16x8*>(r0);
        bf16x8 r0b = *reinterpret_cast<const bf16x8*>(r0 + 8);
        bf16x8 r1a = *reinterpret_cast<const bf16x8*>(r1);
        bf16x8 r1b = *reinterpret_cast<const bf16x8*>(r1 + 8);
        bf16x8 r2a = *reinterpret_cast<const bf16x8*>(r2);
        bf16x8 r2b = *reinterpret_cast<const bf16x8*>(r2 + 8);
        bf16x8 r3a = *reinterpret_cast<const bf16x8*>(r3);
        bf16x8 r3b = *reinterpret_cast<const bf16x8*>(r3 + 8);
        float e0 = __expf(lrelu(aS[s0 * HEADS + head] + adst));
        float e1 = (j + 1 <= dm) ? __expf(lrelu(aS[s1 * HEADS + head] + adst)) : 0.f;
        float e2 = (j + 2 <= dm) ? __expf(lrelu(aS[s2 * HEADS + head] + adst)) : 0.f;
        float e3 = (j + 3 <= dm) ? __expf(lrelu(aS[s3 * HEADS + head] + adst)) : 0.f;
        esum += e0 + e1 + e2 + e3;
#pragma unroll
        for (int c = 0; c < 8; c++) {
            acc[c] += e0 * b2f((unsigned short)r0a[c]) + e1 * b2f((unsigned short)r1a[c])
                    + e2 * b2f((unsigned short)r2a[c]) + e3 * b2f((unsigned short)r3a[c]);
            acc[8 + c] += e0 * b2f((unsigned short)r0b[c]) + e1 * b2f((unsigned short)r1b[c])
                        + e2 * b2f((unsigned short)r2b[c]) + e3 * b2f((unsigned short)r3b[c]);
        }
    }
    float inv = 1.f / (esum + 1e-16f);
    const float* bp = bias + l * 16;
    bf16x8 o0, o1;
#pragma unroll
    for (int c = 0; c < 8; c++) {
        o0[c] = (short)f2b(fmaxf(acc[c] * inv + bp[c], 0.f));
        o1[c] = (short)f2b(fmaxf(acc[8 + c] * inv + bp[8 + c], 0.f));
    }
    unsigned short* op = outb + (size_t)node * D1 + l * 16;
    *reinterpret_cast<bf16x8*>(op) = o0;
    *reinterpret_cast<bf16x8*>(op + 8) = o1;
}

extern "C" void kernel_launch(void* const* d_in, const int* in_sizes, int n_in,
                              void* d_out, int out_size, void* d_ws, size_t ws_size,
                              hipStream_t stream) {
    const float* x   = (const float*)d_in[0];
    const void*  ei  = d_in[1];
    const float* W1  = (const float*)d_in[2];
    const float* as1 = (const float*)d_in[3];
    const float* ad1 = (const float*)d_in[4];
    const float* b1  = (const float*)d_in[5];
    const float* W2  = (const float*)d_in[6];
    const float* as2 = (const float*)d_in[7];
    const float* ad2 = (const float*)d_in[8];
    const float* b2  = (const float*)d_in[9];
    const float* fcW = (const float*)d_in[10];
    const float* fcb = (const float*)d_in[11];
    float* out = (float*)d_out;

    char* ws = (char*)d_ws;
    size_t o = 0;
    auto carve = [&](size_t bytes) -> char* {
        char* p = ws + o;
        o = (o + bytes + 255) & ~(size_t)255;
        return p;
    };
    unsigned short* xb   = (unsigned short*)carve((size_t)NN * IN_DIM * 2);
    unsigned short* hb   = (unsigned short*)carve((size_t)NN * D1 * 2);
    unsigned short* x2b  = (unsigned short*)carve((size_t)NN * D1 * 2);
    unsigned short* W1t  = (unsigned short*)carve((size_t)D1 * IN_DIM * 2);
    unsigned short* W2t  = (unsigned short*)carve((size_t)D1 * D1 * 2);
    unsigned short* fcWt = (unsigned short*)carve((size_t)OUT_DIM * D1 * 2);
    float* aS   = (float*)carve((size_t)NN * HEADS * 4);
    float* aD   = (float*)carve((size_t)NN * HEADS * 4);
    int* counts = (int*)carve((size_t)NN * 4);
    int* cursor = (int*)carve((size_t)NN * 4);
    int* indptr = (int*)carve((size_t)(NN + 1) * 4);
    int* csr_src= (int*)carve((size_t)NET * 4);
    (void)ws_size; (void)in_sizes; (void)n_in; (void)out_size;

    const int MB128 = (NN + 127) / 128;  // 79
    const int MB64  = (NN + 63) / 64;    // 157
    const int G1 = MB128 * (D1 / 64);    // 1264
    const int GF = MB64 * (OUT_DIM / 64);// 1256
    const int NATT = NN / 4;             // 2500

    // 1. zero counts/cursor
    zero_kernel<<<(NN + 255) / 256, 256, 0, stream>>>(counts, cursor);
    // 2. setup: cvt + transposes + CSR count
    setup_kernel<<<CVT_NB + TP1_NB + TP2_NB + TP3_NB + CNT_NB, 256, 0, stream>>>(
        ei, counts, x, xb, W1, W1t, W2, W2t, fcW, fcWt);
    // 3. gemm1 (+1 block: CSR scan)
    gemmT<128, 64><<<G1 + 1, 256, 0, stream>>>(xb, W1t, nullptr, nullptr, hb,
                                               NN, D1, IN_DIM, D1 / 64, G1,
                                               counts, indptr);
    // 4. att1 + CSR fill
    att_fill_kernel<<<NATT + CNT_NB, 256, 0, stream>>>(hb, as1, ad1, aS, aD,
                                                       ei, indptr, cursor, csr_src, NATT);
    // 5. agg1
    agg_kernel<<<NATT, 256, 0, stream>>>(hb, aS, aD, indptr, csr_src, b1, x2b);
    // 6. gemm2
    gemmT<128, 64><<<G1, 256, 0, stream>>>(x2b, W2t, nullptr, nullptr, hb,
                                           NN, D1, D1, D1 / 64, G1,
                                           nullptr, nullptr);
    // 7. att2
    att_fill_kernel<<<NATT, 256, 0, stream>>>(hb, as2, ad2, aS, aD,
                                              ei, indptr, cursor, csr_src, NATT);
    // 8. agg2
    agg_kernel<<<NATT, 256, 0, stream>>>(hb, aS, aD, indptr, csr_src, b2, x2b);
    // 9. final fc (bias, f32 out)
    gemmT<64, 64><<<GF, 256, 0, stream>>>(x2b, fcWt, fcb, out, nullptr,
                                          NN, OUT_DIM, D1, OUT_DIM / 64, GF,
                                          nullptr, nullptr);
}